// Round 3
// baseline (123.446 us; speedup 1.0000x reference)
//
#include <hip/hip_runtime.h>

// ChannelKiller: out[b,c,s] = (c==0) ? x[b,c,s] : 0
// x: [16, 8, 1048576] fp32.
// Single-dispatch block specialization: NZB blocks zero channels 1..7
// (448 MiB pure-store), NCB blocks copy channel 0 (64 MiB r + 64 MiB w).
// Blocks own CONTIGUOUS chunks (sequential 4KB steps) for DRAM row locality;
// read and write streams overlap in one dispatch (no serial phase / drain).

typedef float f32x4 __attribute__((ext_vector_type(4)));

#define S_LOG2 18                   // float4 per channel row = 2^18
#define ZPB (7 << S_LOG2)           // zero float4 per batch (ch 1..7) = 1835008
#define NB 16
#define ZT (NB * ZPB)               // 29360128 zero float4 total
#define CT (NB << S_LOG2)           // 4194304 copy float4 total

#define NZB 1664                    // zero blocks   (traffic 470 MB -> ~282 KB/blk)
#define NCB 384                     // copy blocks   (traffic 268 MB -> ~699 KB/blk... r+w)
#define BLOCK 256

__global__ __launch_bounds__(BLOCK)
void ChannelKiller_54365696033605_kernel(const f32x4* __restrict__ x,
                                         f32x4* __restrict__ out) {
    const int bid = blockIdx.x;
    const int tid = threadIdx.x;
    const f32x4 zf = {0.f, 0.f, 0.f, 0.f};

    if (bid < NZB) {
        // ---- zero specialization: contiguous chunk of the zero-linear space
        const int chunk = (((ZT + NZB - 1) / NZB) + BLOCK - 1) / BLOCK * BLOCK; // 17664
        const int z0 = bid * chunk;
        const int z1 = (z0 + chunk < ZT) ? z0 + chunk : ZT;
        for (int z = z0 + tid; z < z1; z += BLOCK) {
            // zero-linear -> flat: batch = z / ZPB (compile-time magic div)
            int batch = z / ZPB;
            int rem = z - batch * ZPB;
            int addr = (batch << 21) + (1 << S_LOG2) + rem;  // skip channel 0
            out[addr] = zf;
        }
    } else {
        // ---- copy specialization: channel-0 float4s, contiguous chunk
        const int cid = bid - NZB;
        const int chunk = (((CT + NCB - 1) / NCB) + BLOCK - 1) / BLOCK * BLOCK; // 11008
        const int z0 = cid * chunk;
        const int z1 = (z0 + chunk < CT) ? z0 + chunk : CT;
        for (int z = z0 + tid; z < z1; z += BLOCK) {
            int addr = ((z >> S_LOG2) << 21) | (z & ((1 << S_LOG2) - 1));
            out[addr] = x[addr];
        }
    }
}

extern "C" void kernel_launch(void* const* d_in, const int* in_sizes, int n_in,
                              void* d_out, int out_size, void* d_ws, size_t ws_size,
                              hipStream_t stream) {
    const f32x4* x = (const f32x4*)d_in[0];
    f32x4* out = (f32x4*)d_out;
    // 2048 blocks x 256 thr = 8 blocks/CU resident -> zero & copy run concurrently
    ChannelKiller_54365696033605_kernel<<<NZB + NCB, BLOCK, 0, stream>>>(x, out);
}

// Round 4
// 107.693 us; speedup vs baseline: 1.1463x; 1.1463x over previous
//
#include <hip/hip_runtime.h>

// ChannelKiller: out[b,c,s] = (c==0) ? x[b,c,s] : 0
// x: [16, 8, 1048576] fp32.
// R4: let the runtime's fillBufferAligned (measured 6.73-6.86 TB/s on this
// device) write the zeros: one 512 MiB hipMemsetAsync over all of out, then
// overwrite channel 0 with a dense 1-element-per-thread copy (64 MiB r+w).
// Both ops are stream-ordered and graph-capturable.

typedef float f32x4 __attribute__((ext_vector_type(4)));

#define S_LOG2 18   // float4 per channel row = 1048576/4 = 2^18

// One float4 per thread: i in [0, 16*2^18), flat addr skips channels 1..7.
// Max outstanding loads (1 per lane, no loop-carried serialization).
__global__ __launch_bounds__(256)
void ChannelKiller_copy_kernel(const f32x4* __restrict__ x,
                               f32x4* __restrict__ out) {
    int i = blockIdx.x * blockDim.x + threadIdx.x;
    // batch = i >> 18; within-row = i & (2^18-1); batch stride = 8*2^18 = 2^21
    int addr = ((i >> S_LOG2) << (S_LOG2 + 3)) | (i & ((1 << S_LOG2) - 1));
    out[addr] = x[addr];
}

extern "C" void kernel_launch(void* const* d_in, const int* in_sizes, int n_in,
                              void* d_out, int out_size, void* d_ws, size_t ws_size,
                              hipStream_t stream) {
    const f32x4* x = (const f32x4*)d_in[0];
    f32x4* out = (f32x4*)d_out;

    // Phase 1: zero everything (runs as rocclr fillBufferAligned, ~6.8 TB/s).
    hipMemsetAsync(d_out, 0, (size_t)out_size * sizeof(float), stream);

    // Phase 2: copy channel 0. 16 batches * 2^18 float4 = 4194304 threads
    // = 16384 blocks x 256. Exact cover, no bounds check needed.
    ChannelKiller_copy_kernel<<<16384, 256, 0, stream>>>(x, out);
}